// Round 5
// baseline (431.966 us; speedup 1.0000x reference)
//
#include <hip/hip_runtime.h>
#include <hip/hip_cooperative_groups.h>
namespace cg = cooperative_groups;

#define WID 224
#define HGT 224
#define HWp (224*224)      // 50176
#define CHW (3*224*224)    // 150528
#define NB  64
#define ST  784            // per-image stats: [0]=mu, [1..3]=lo, [4..6]=hi, [16..783]=lut[3][256]
#define NSL 1024           // slice tasks in phase 0 (64 images x 16 slices)
#define SL   16
#define SCH  (HWp/SL)      // 3136 px per slice
#define NT   (NB*CHW/1024) // 9408 tiles of 1024 px
#define TPI  147           // tiles per image
#define TPC  49            // tiles per channel

__device__ __forceinline__ float clip255(float v){ return fminf(fmaxf(v, 0.f), 255.f); }

__device__ __forceinline__ float blk_reduce(float v, float* red, int tid, int op){
    // op: 0=sum 1=min 2=max
    red[tid] = v; __syncthreads();
    for (int s = 128; s > 0; s >>= 1){
        if (tid < s){
            float a = red[tid], b = red[tid+s];
            red[tid] = (op==0) ? a+b : (op==1 ? fminf(a,b) : fmaxf(a,b));
        }
        __syncthreads();
    }
    float r = red[0]; __syncthreads();
    return r;
}

__device__ __forceinline__ void build_lut(const int* h, float* lut){
    int step = (HWp - h[255]) / 255;
    int cum = 0;                                   // exclusive cumsum
    for (int i = 0; i < 256; i++){
        int l = (step > 0) ? min(max((cum + (step >> 1)) / step, 0), 255) : i;
        lut[i] = (float)l;
        cum += h[i];
    }
}

__device__ __forceinline__ float samp(const float* __restrict__ pl, float yi, float xi, float scl){
    if (xi < 0.f || xi > (float)(WID-1) || yi < 0.f || yi > (float)(HGT-1)) return 0.f;
    return pl[(int)yi * WID + (int)xi] * scl;
}

// Process one 1024-px tile (4 px/thread), write dst, return outputs in o[4] and (b,c).
__device__ __forceinline__ void apply_tile(const float* __restrict__ src,
                                           float* __restrict__ dst,
                                           int t, int tid,
                                           const int* __restrict__ opi,
                                           const float* __restrict__ mags,
                                           const int* __restrict__ mask,
                                           const float* __restrict__ stats,
                                           float scl, int finalOut,
                                           float o[4], int* ob, int* oc)
{
    int idx = t*1024 + tid*4;
    int b = idx / CHW;
    int r = idx - b*CHW;
    int c = r / HWp;
    int p = r - c*HWp;
    int y = p / WID;
    int x = p - y*WID;
    const float* img = src + (size_t)b * CHW;
    const float* pl  = img + c*HWp;
    float4 v4 = *(const float4*)(pl + p);
    float iv[4] = {v4.x*scl, v4.y*scl, v4.z*scl, v4.w*scl};
    int   j  = opi[b];
    int   ap = mask[b];
    float m  = mags[b];
    const float* st = stats + (size_t)b * ST;

    if (!ap) {
        #pragma unroll
        for (int k = 0; k < 4; k++) o[k] = iv[k];
    } else {
        switch (j){
        case 0: case 1: case 2: case 3: case 4: {   // affine family
            float a = 1.f, bb = 0.f, cc = 0.f, dd = 0.f, ee = 1.f, ff = 0.f;
            if (j == 0)      bb = -0.3f + 0.6f*m;
            else if (j == 1) dd = -0.3f + 0.6f*m;
            else if (j == 2) cc = (-0.45f + 0.9f*m) * (float)WID;
            else if (j == 3) ff = (-0.45f + 0.9f*m) * (float)HGT;
            else {
                float deg = -30.f + 60.f*m;
                float rad = deg * (float)(3.14159265358979323846/180.0);
                float cs = cosf(rad), sn = sinf(rad);
                float cx = (WID-1)*0.5f, cy = (HGT-1)*0.5f;
                a = cs; bb = sn; dd = -sn; ee = cs;
                cc = cx - cs*cx - sn*cy;
                ff = cy + sn*cx - cs*cy;
            }
            float yf = (float)y;
            #pragma unroll
            for (int k = 0; k < 4; k++){
                float xf = (float)(x + k);
                float sx = a*xf + bb*yf + cc;
                float sy = dd*xf + ee*yf + ff;
                float x0f = floorf(sx), y0f = floorf(sy);
                float wx = sx - x0f, wy = sy - y0f;
                float v00 = samp(pl, y0f,     x0f,     scl);
                float v01 = samp(pl, y0f,     x0f+1.f, scl);
                float v10 = samp(pl, y0f+1.f, x0f,     scl);
                float v11 = samp(pl, y0f+1.f, x0f+1.f, scl);
                float top = v00*(1.f-wx) + v01*wx;
                float bot = v10*(1.f-wx) + v11*wx;
                o[k] = top*(1.f-wy) + bot*wy;
            }
            break; }
        case 5: {
            float f = 0.1f + 1.8f*m;
            #pragma unroll
            for (int k = 0; k < 4; k++) o[k] = clip255(iv[k]*f);
            break; }
        case 6: {
            float4 r4 = *(const float4*)(img + p);
            float4 g4 = *(const float4*)(img + HWp + p);
            float4 b4 = *(const float4*)(img + 2*HWp + p);
            float rr[4] = {r4.x*scl, r4.y*scl, r4.z*scl, r4.w*scl};
            float gg[4] = {g4.x*scl, g4.y*scl, g4.z*scl, g4.w*scl};
            float bl[4] = {b4.x*scl, b4.y*scl, b4.z*scl, b4.w*scl};
            float f = 0.1f + 1.8f*m;
            #pragma unroll
            for (int k = 0; k < 4; k++){
                float g = 0.299f*rr[k] + 0.587f*gg[k] + 0.114f*bl[k];
                o[k] = clip255(g + f*(iv[k] - g));
            }
            break; }
        case 7: {
            float f = 0.1f + 1.8f*m;
            #pragma unroll
            for (int k = 0; k < 4; k++){
                int xx = x + k;
                if (y == 0 || y == HGT-1 || xx == 0 || xx == WID-1) o[k] = iv[k];
                else {
                    int q = p + k;
                    float s8 = pl[q-WID-1] + pl[q-WID] + pl[q-WID+1]
                             + pl[q-1]     + pl[q+1]
                             + pl[q+WID-1] + pl[q+WID] + pl[q+WID+1];
                    float blur = (s8*scl + 5.f*iv[k]) * (1.f/13.f);
                    o[k] = clip255(blur + f*(iv[k] - blur));
                }
            }
            break; }
        case 8: {
            float mu = st[0];
            float f = 0.1f + 1.8f*m;
            #pragma unroll
            for (int k = 0; k < 4; k++) o[k] = clip255(mu + f*(iv[k] - mu));
            break; }
        case 9: {
            float thr = 256.f*m;
            #pragma unroll
            for (int k = 0; k < 4; k++) o[k] = (iv[k] < thr) ? iv[k] : 255.f - iv[k];
            break; }
        case 10: {
            float q = exp2f(rintf(4.f*m));
            #pragma unroll
            for (int k = 0; k < 4; k++) o[k] = floorf(iv[k]/q)*q;
            break; }
        case 11: {
            #pragma unroll
            for (int k = 0; k < 4; k++){
                int ivi = min(max((int)rintf(iv[k]), 0), 255);
                o[k] = st[16 + c*256 + ivi];
            }
            break; }
        case 12: {
            float lo = st[1+c], hi = st[4+c];
            float sc = 255.f / fmaxf(hi - lo, 1e-6f);
            #pragma unroll
            for (int k = 0; k < 4; k++)
                o[k] = (hi > lo) ? clip255((iv[k] - lo) * sc) : iv[k];
            break; }
        default:
            #pragma unroll
            for (int k = 0; k < 4; k++) o[k] = iv[k];
            break;
        }
    }

    float4 w;
    if (finalOut){
        w.x = fminf(fmaxf(o[0]*(1.f/255.f), 0.f), 1.f);
        w.y = fminf(fmaxf(o[1]*(1.f/255.f), 0.f), 1.f);
        w.z = fminf(fmaxf(o[2]*(1.f/255.f), 0.f), 1.f);
        w.w = fminf(fmaxf(o[3]*(1.f/255.f), 0.f), 1.f);
    } else {
        w.x = o[0]; w.y = o[1]; w.z = o[2]; w.w = o[3];
    }
    *(float4*)(dst + idx) = w;
    *ob = b; *oc = c;
}

// ---------------- workspace layout ----------------
struct WS {
    float* scale;   // [0]
    float* pmaxA;   // 1024
    float* psum0;   // 1024
    float* pmin0;   // 3072
    float* pmax0;   // 3072
    int*   phist0;  // 1024*1536
    int*   hist1;   // 64*768
    float* psum1;   // 9408
    float* pmin1;   // 9408
    float* pmax1;   // 9408
    float* stats0;  // 64*784
    float* stats1;  // 64*784
    float* inter;   // 9,633,792
};
__host__ __device__ __forceinline__ WS get_ws(float* wsf){
    WS w;
    w.scale  = wsf;
    w.pmaxA  = wsf + 64;
    w.psum0  = wsf + 1088;
    w.pmin0  = wsf + 2112;
    w.pmax0  = wsf + 5184;
    w.phist0 = (int*)(wsf + 8256);
    w.hist1  = (int*)(wsf + 1581120);
    w.psum1  = wsf + 1630272;
    w.pmin1  = wsf + 1639680;
    w.pmax1  = wsf + 1649088;
    w.stats0 = wsf + 1658496;
    w.stats1 = wsf + 1708672;
    w.inter  = wsf + 1758848;
    return w;
}

// ---------------- phase bodies (grid-stride; any grid size) ----------------
__device__ void phase0_dev(const float* __restrict__ x, const int* __restrict__ op0,
                           const int* __restrict__ mk0, WS w, float* red, int* sh)
{
    int tid = threadIdx.x;
    for (int i = blockIdx.x*256 + tid; i < NB*768; i += gridDim.x*256) w.hist1[i] = 0;
    const float GW[3] = {0.299f, 0.587f, 0.114f};
    for (int wk = blockIdx.x; wk < NSL; wk += gridDim.x){
        int b = wk >> 4, s = wk & (SL-1);
        int j = op0[b], ap = mk0[b];
        bool needSum  = ap && (j == 8);
        bool needMM   = ap && (j == 12);
        bool needHist = ap && (j == 11);
        const float* img = x + (size_t)b * CHW;
        int p0 = s * SCH;
        float mx = 0.f, gs = 0.f;
        for (int c = 0; c < 3; c++){
            const float* pl = img + c*HWp + p0;
            float lo = 3.4e38f, hi = 0.f, cs = 0.f;
            for (int p = tid*4; p < SCH; p += 1024){
                float4 v = *(const float4*)(pl + p);
                float m4 = fmaxf(fmaxf(v.x, v.y), fmaxf(v.z, v.w));
                mx = fmaxf(mx, m4);
                if (needMM){ hi = fmaxf(hi, m4); lo = fminf(lo, fminf(fminf(v.x,v.y), fminf(v.z,v.w))); }
                if (needSum) cs += (v.x + v.y) + (v.z + v.w);
            }
            if (needSum) gs += GW[c] * cs;
            if (needMM){
                float l = blk_reduce(lo, red, tid, 1);
                if (!tid) w.pmin0[wk*3 + c] = l;
                float h = blk_reduce(hi, red, tid, 2);
                if (!tid) w.pmax0[wk*3 + c] = h;
            }
        }
        float bm = blk_reduce(mx, red, tid, 2);
        if (!tid) w.pmaxA[wk] = bm;
        if (needSum){
            float t = blk_reduce(gs, red, tid, 0);
            if (!tid) w.psum0[wk] = t;
        }
        if (needHist){
            for (int i = tid; i < 1536; i += 256) sh[i] = 0;
            __syncthreads();
            for (int c = 0; c < 3; c++){
                const float* pl = img + c*HWp + p0;
                for (int p = tid; p < SCH; p += 256){
                    float v = pl[p];
                    atomicAdd(&sh[c*256 + min(max((int)rintf(v), 0), 255)], 1);
                    atomicAdd(&sh[768 + c*256 + min(max((int)rintf(v*255.f), 0), 255)], 1);
                }
            }
            __syncthreads();
            for (int i = tid; i < 1536; i += 256) w.phist0[wk*1536 + i] = sh[i];
            __syncthreads();
        }
    }
}

__device__ void phase1_dev(const int* __restrict__ op0, const int* __restrict__ mk0,
                           WS w, float* red, int* sh)
{
    int tid = threadIdx.x;
    for (int b = blockIdx.x; b < NB; b += gridDim.x){
        float m = 0.f;
        for (int i = tid; i < NSL; i += 256) m = fmaxf(m, w.pmaxA[i]);
        float gm = blk_reduce(m, red, tid, 2);
        float scl = (gm <= 1.0f) ? 255.f : 1.f;
        if (!tid && b == 0) *w.scale = scl;
        int j = op0[b];
        if (!mk0[b]) continue;
        float* st = w.stats0 + (size_t)b * ST;
        if (j == 8){
            if (!tid){
                float t = 0.f;
                for (int s = 0; s < SL; s++) t += w.psum0[b*SL + s];
                st[0] = t * scl * (1.f/(float)HWp);
            }
        } else if (j == 12){
            if (tid < 3){
                float lo = 3.4e38f, hi = 0.f;
                for (int s = 0; s < SL; s++){
                    lo = fminf(lo, w.pmin0[(b*SL+s)*3 + tid]);
                    hi = fmaxf(hi, w.pmax0[(b*SL+s)*3 + tid]);
                }
                st[1+tid] = lo * scl;
                st[4+tid] = hi * scl;
            }
        } else if (j == 11){
            int d = (scl == 255.f) ? 1 : 0;
            for (int i = tid; i < 768; i += 256){
                int t = 0;
                for (int s = 0; s < SL; s++) t += w.phist0[(b*SL+s)*1536 + d*768 + i];
                sh[i] = t;
            }
            __syncthreads();
            if (tid < 3) build_lut(sh + tid*256, st + 16 + tid*256);
            __syncthreads();
        }
    }
}

__device__ void phase2_dev(const float* __restrict__ x,
                           const float* __restrict__ ra,
                           const int* __restrict__ op, const int* __restrict__ mask,
                           WS w, float* red, int* sh)
{
    int tid = threadIdx.x;
    const int *op0 = op, *op1 = op + NB, *mk0 = mask, *mk1 = mask + NB;
    float scl = *w.scale;
    const float GW[3] = {0.299f, 0.587f, 0.114f};
    for (int t = blockIdx.x; t < NT; t += gridDim.x){
        float o[4]; int b, c;
        apply_tile(x, w.inter, t, tid, op0, ra, mk0, w.stats0, scl, 0, o, &b, &c);
        int jn = op1[b];
        if (mk1[b] && (jn == 8 || jn == 11 || jn == 12)){
            if (jn == 8){
                float s4 = (o[0] + o[1]) + (o[2] + o[3]);
                float tot = blk_reduce(s4, red, tid, 0);
                if (!tid) w.psum1[t] = tot * GW[c];
            } else if (jn == 12){
                float lo = fminf(fminf(o[0],o[1]), fminf(o[2],o[3]));
                float hi = fmaxf(fmaxf(o[0],o[1]), fmaxf(o[2],o[3]));
                float l = blk_reduce(lo, red, tid, 1);
                if (!tid) w.pmin1[t] = l;
                float h = blk_reduce(hi, red, tid, 2);
                if (!tid) w.pmax1[t] = h;
            } else {
                sh[tid] = 0;
                __syncthreads();
                #pragma unroll
                for (int k = 0; k < 4; k++)
                    atomicAdd(&sh[min(max((int)rintf(o[k]), 0), 255)], 1);
                __syncthreads();
                int v = sh[tid];
                if (v) atomicAdd(&w.hist1[b*768 + c*256 + tid], v);
                __syncthreads();
            }
        }
    }
}

__device__ void phase3_dev(const int* __restrict__ op, const int* __restrict__ mask,
                           WS w, float* red, int* sh)
{
    int tid = threadIdx.x;
    const int *op1 = op + NB, *mk1 = mask + NB;
    for (int b = blockIdx.x; b < NB; b += gridDim.x){
        int j = op1[b];
        if (!mk1[b]) continue;
        float* st = w.stats1 + (size_t)b * ST;
        if (j == 8){
            float t = 0.f;
            for (int i = tid; i < TPI; i += 256) t += w.psum1[b*TPI + i];
            float tot = blk_reduce(t, red, tid, 0);
            if (!tid) st[0] = tot * (1.f/(float)HWp);
        } else if (j == 12){
            if (tid < 3){
                float lo = 3.4e38f, hi = 0.f;
                for (int k = 0; k < TPC; k++){
                    lo = fminf(lo, w.pmin1[b*TPI + tid*TPC + k]);
                    hi = fmaxf(hi, w.pmax1[b*TPI + tid*TPC + k]);
                }
                st[1+tid] = lo;
                st[4+tid] = hi;
            }
        } else if (j == 11){
            for (int i = tid; i < 768; i += 256) sh[i] = w.hist1[b*768 + i];
            __syncthreads();
            if (tid < 3) build_lut(sh + tid*256, st + 16 + tid*256);
            __syncthreads();
        }
    }
}

__device__ void phase4_dev(const float* __restrict__ ra,
                           const int* __restrict__ op, const int* __restrict__ mask,
                           float* __restrict__ out, WS w)
{
    int tid = threadIdx.x;
    const int *op1 = op + NB, *mk1 = mask + NB;
    for (int t = blockIdx.x; t < NT; t += gridDim.x){
        float o[4]; int b, c;
        apply_tile(w.inter, out, t, tid, op1, ra + NB, mk1, w.stats1, 1.f, 1, o, &b, &c);
    }
}

// ---------------- cooperative mega kernel ----------------
__global__ __launch_bounds__(256, 4)
void mega_kernel(const float* __restrict__ x, const float* __restrict__ ra,
                 const int* __restrict__ op, const int* __restrict__ mask,
                 float* __restrict__ out, float* __restrict__ wsf)
{
    __shared__ float red[256];
    __shared__ int sh[1536];
    WS w = get_ws(wsf);
    cg::grid_group grid = cg::this_grid();
    phase0_dev(x, op, mask, w, red, sh);
    grid.sync();
    phase1_dev(op, mask, w, red, sh);
    grid.sync();
    phase2_dev(x, ra, op, mask, w, red, sh);
    grid.sync();
    phase3_dev(op, mask, w, red, sh);
    grid.sync();
    phase4_dev(ra, op, mask, out, w);
}

// ---------------- fallback: same phases as separate kernels ----------------
__global__ void k_phase0(const float* x, const int* op, const int* mask, float* wsf){
    __shared__ float red[256]; __shared__ int sh[1536];
    phase0_dev(x, op, mask, get_ws(wsf), red, sh);
}
__global__ void k_phase1(const int* op, const int* mask, float* wsf){
    __shared__ float red[256]; __shared__ int sh[1536];
    phase1_dev(op, mask, get_ws(wsf), red, sh);
}
__global__ void k_phase2(const float* x, const float* ra, const int* op, const int* mask, float* wsf){
    __shared__ float red[256]; __shared__ int sh[1536];
    phase2_dev(x, ra, op, mask, get_ws(wsf), red, sh);
}
__global__ void k_phase3(const int* op, const int* mask, float* wsf){
    __shared__ float red[256]; __shared__ int sh[1536];
    phase3_dev(op, mask, get_ws(wsf), red, sh);
}
__global__ void k_phase4(const float* ra, const int* op, const int* mask, float* out, float* wsf){
    phase4_dev(ra, op, mask, out, get_ws(wsf));
}

extern "C" void kernel_launch(void* const* d_in, const int* in_sizes, int n_in,
                              void* d_out, int out_size, void* d_ws, size_t ws_size,
                              hipStream_t stream) {
    const float* x    = (const float*)d_in[0];
    const float* ra   = (const float*)d_in[1];
    const int*   op   = (const int*)d_in[2];
    const int*   mask = (const int*)d_in[3];
    float* out = (float*)d_out;
    float* wsf = (float*)d_ws;

    int maxPerCU = 0;
    hipError_t qe = hipOccupancyMaxActiveBlocksPerMultiprocessor(
        &maxPerCU, (const void*)mega_kernel, 256, 0);

    hipError_t le = hipErrorUnknown;
    if (qe == hipSuccess && maxPerCU > 0){
        int grid = maxPerCU * 256;           // 256 CUs on MI355X
        if (grid > 1024) grid = 1024;
        void* args[] = {(void*)&x, (void*)&ra, (void*)&op, (void*)&mask, (void*)&out, (void*)&wsf};
        le = hipLaunchCooperativeKernel((const void*)mega_kernel,
                                        dim3(grid), dim3(256), args, 0, stream);
    }
    if (le != hipSuccess){
        (void)hipGetLastError();             // clear the error; use classic pipeline
        k_phase0<<<1024, 256, 0, stream>>>(x, op, mask, wsf);
        k_phase1<<<NB,   256, 0, stream>>>(op, mask, wsf);
        k_phase2<<<NT,   256, 0, stream>>>(x, ra, op, mask, wsf);
        k_phase3<<<NB,   256, 0, stream>>>(op, mask, wsf);
        k_phase4<<<NT,   256, 0, stream>>>(ra, op, mask, out, wsf);
    }
}